// Round 5
// baseline (2402.020 us; speedup 1.0000x reference)
//
#include <hip/hip_runtime.h>
#include <math.h>

// SE layer: x[32,256,64,64] f32, w1[16,256], w2[256,256]
// pooled = mean(x, HW); y = relu(pooled @ w1^T); outer = y⊗y (flat 256);
// s = sigmoid(outer @ w2^T); out = x * s[b,c]
//
// Single-pass fused kernel: each block owns one (b,c) slice (16KB), keeps it
// in REGISTERS across the pool->fc->scale dependency. Per-batch producer-
// consumer sync: last-arriving block of each batch computes the fc chain and
// releases a flag; peers spin (s_sleep). x is read from HBM exactly once.

#define B 32
#define C 256
#define HID 16
#define BD 256       // HID*HID
#define HW 4096      // 64*64

typedef float vf4 __attribute__((ext_vector_type(4)));

// zero the per-batch arrive counters A[32] and flags F[32] (ws is 0xAA-poisoned)
__global__ __launch_bounds__(64) void init_kernel(unsigned int* __restrict__ ctr) {
    ctr[threadIdx.x] = 0u;
}

__global__ __launch_bounds__(256) void se_onepass(const float* __restrict__ x,
                                                  const float* __restrict__ w1,
                                                  const float* __restrict__ w2,
                                                  float* __restrict__ out,
                                                  float* __restrict__ pooled,
                                                  float* __restrict__ s_ws,
                                                  unsigned int* __restrict__ A,
                                                  unsigned int* __restrict__ F) {
    const int bc = blockIdx.x;
    const int b  = bc >> 8;
    const int t  = threadIdx.x;

    // ---- load own slice into registers (16 floats/thread) + pool ----
    const vf4* xp = reinterpret_cast<const vf4*>(x + (size_t)bc * HW);
    vf4 v0 = xp[t];
    vf4 v1 = xp[t + 256];
    vf4 v2 = xp[t + 512];
    vf4 v3 = xp[t + 768];

    float sum = ((v0.x + v0.y) + (v0.z + v0.w)) + ((v1.x + v1.y) + (v1.z + v1.w))
              + ((v2.x + v2.y) + (v2.z + v2.w)) + ((v3.x + v3.y) + (v3.z + v3.w));
#pragma unroll
    for (int off = 32; off > 0; off >>= 1) sum += __shfl_down(sum, off, 64);

    __shared__ float red[4];
    __shared__ int is_last;
    __shared__ float pl[C];
    __shared__ float yv[HID];
    __shared__ float outer_s[BD];

    if ((t & 63) == 0) red[t >> 6] = sum;
    __syncthreads();
    if (t == 0) {
        float mean = ((red[0] + red[1]) + (red[2] + red[3])) * (1.0f / (float)HW);
        __hip_atomic_store(&pooled[bc], mean, __ATOMIC_RELEASE, __HIP_MEMORY_SCOPE_AGENT);
        unsigned int prev = __hip_atomic_fetch_add(&A[b], 1u, __ATOMIC_ACQ_REL,
                                                   __HIP_MEMORY_SCOPE_AGENT);
        is_last = (prev == (unsigned int)(C - 1)) ? 1 : 0;
    }
    __syncthreads();

    // ---- last-arriving block of batch b computes fc1+relu+outer+fc2+sigmoid ----
    if (is_last) {
        pl[t] = __hip_atomic_load(&pooled[b * C + t], __ATOMIC_ACQUIRE,
                                  __HIP_MEMORY_SCOPE_AGENT);
        __syncthreads();
        if (t < HID) {
            float acc = 0.f;
            const float* w1r = w1 + t * C;
#pragma unroll 8
            for (int c = 0; c < C; ++c) acc += pl[c] * w1r[c];
            yv[t] = fmaxf(acc, 0.f);
        }
        __syncthreads();
        outer_s[t] = yv[t >> 4] * yv[t & 15];
        __syncthreads();
        const vf4* w2r = reinterpret_cast<const vf4*>(w2 + (size_t)t * BD);
        const vf4* orow = reinterpret_cast<const vf4*>(outer_s);
        float acc = 0.f;
#pragma unroll 8
        for (int d4 = 0; d4 < BD / 4; ++d4) {
            vf4 w = w2r[d4];
            vf4 o = orow[d4];
            acc += w.x * o.x + w.y * o.y + w.z * o.z + w.w * o.w;
        }
        float sv = 1.0f / (1.0f + expf(-acc));
        __hip_atomic_store(&s_ws[b * C + t], sv, __ATOMIC_RELEASE,
                           __HIP_MEMORY_SCOPE_AGENT);
        __syncthreads();
        if (t == 0) {
            __hip_atomic_store(&F[b], 1u, __ATOMIC_RELEASE, __HIP_MEMORY_SCOPE_AGENT);
        }
    }

    // ---- wait for this batch's scale vector ----
    if (t == 0) {
        while (__hip_atomic_load(&F[b], __ATOMIC_ACQUIRE, __HIP_MEMORY_SCOPE_AGENT) == 0u) {
            __builtin_amdgcn_s_sleep(8);
        }
    }
    __syncthreads();

    const float sc = __hip_atomic_load(&s_ws[bc], __ATOMIC_ACQUIRE,
                                       __HIP_MEMORY_SCOPE_AGENT);

    // ---- scale from registers, stream out ----
    v0 *= sc; v1 *= sc; v2 *= sc; v3 *= sc;
    vf4* op = reinterpret_cast<vf4*>(out + (size_t)bc * HW);
    __builtin_nontemporal_store(v0, &op[t]);
    __builtin_nontemporal_store(v1, &op[t + 256]);
    __builtin_nontemporal_store(v2, &op[t + 512]);
    __builtin_nontemporal_store(v3, &op[t + 768]);
}

extern "C" void kernel_launch(void* const* d_in, const int* in_sizes, int n_in,
                              void* d_out, int out_size, void* d_ws, size_t ws_size,
                              hipStream_t stream) {
    const float* x  = (const float*)d_in[0];
    const float* w1 = (const float*)d_in[1];
    const float* w2 = (const float*)d_in[2];
    float* out = (float*)d_out;

    float* pooled = (float*)d_ws;                        // B*C floats (32 KB)
    float* s      = (float*)d_ws + B * C;                // B*C floats (32 KB)
    unsigned int* ctr = (unsigned int*)((char*)d_ws + 2 * B * C * sizeof(float));
    unsigned int* Ar  = ctr;                             // arrive counters [B]
    unsigned int* Fl  = ctr + B;                         // flags [B]

    init_kernel<<<1, 64, 0, stream>>>(ctr);              // zeros A[32] + F[32]
    se_onepass<<<B * C, 256, 0, stream>>>(x, w1, w2, out, pooled, s, Ar, Fl);
}

// Round 6
// 67.582 us; speedup vs baseline: 35.5424x; 35.5424x over previous
//
#include <hip/hip_runtime.h>
#include <math.h>

// SE layer: x[32,256,64,64] f32, w1[16,256], w2[256,256]
// pooled = mean(x, HW); y = relu(pooled @ w1^T); outer = y⊗y (flat 256);
// s = sigmoid(outer @ w2^T); out = x * s[b,c]
//
// Chunked 2-phase structure for L3 reuse: per 16-batch chunk (67 MB),
// pool(chunk) then scale(chunk). During scale, chunk-x + chunk-out = 134 MB
// << 256 MB Infinity Cache, so the x re-read is L3-hit instead of HBM.
// fc is recomputed redundantly inside every scale block (4.6K MACs,
// block-parallel, overlapped with the x register loads) — no 3rd kernel,
// no atomics, no cross-block sync. 4 graph nodes: P0,S0,P1,S1.

#define B 32
#define C 256
#define HID 16
#define BD 256       // HID*HID
#define HW 4096      // 64*64
#define CHUNKB 16    // batches per chunk

typedef float vf4 __attribute__((ext_vector_type(4)));

// ---------------- pool: one block per (b,c) slice ----------------
__global__ __launch_bounds__(256) void pool_kernel(const float* __restrict__ x,
                                                   float* __restrict__ pooled,
                                                   int bc0) {
    const int bc = bc0 + blockIdx.x;
    const vf4* xp = reinterpret_cast<const vf4*>(x + (size_t)bc * HW);
    const int t = threadIdx.x;
    float sum = 0.f;
#pragma unroll
    for (int k = 0; k < 4; ++k) {
        vf4 v = xp[t + k * 256];
        sum += (v.x + v.y) + (v.z + v.w);
    }
#pragma unroll
    for (int off = 32; off > 0; off >>= 1) sum += __shfl_down(sum, off, 64);
    __shared__ float red[4];
    if ((t & 63) == 0) red[t >> 6] = sum;
    __syncthreads();
    if (t == 0)
        pooled[bc] = ((red[0] + red[1]) + (red[2] + red[3])) * (1.0f / (float)HW);
}

// ------- scale: one block per (b,c); recomputes fc for its channel -------
__global__ __launch_bounds__(256) void scale_kernel(const float* __restrict__ x,
                                                    const float* __restrict__ pooled,
                                                    const float* __restrict__ w1,
                                                    const float* __restrict__ w2,
                                                    float* __restrict__ out,
                                                    int bc0) {
    const int bc = bc0 + blockIdx.x;
    const int b = bc >> 8, c0 = bc & 255;
    const int t = threadIdx.x;

    // issue x loads early; fc compute hides the HBM/L3 latency
    const vf4* xp = reinterpret_cast<const vf4*>(x + (size_t)bc * HW);
    vf4 v0 = xp[t];
    vf4 v1 = xp[t + 256];
    vf4 v2 = xp[t + 512];
    vf4 v3 = xp[t + 768];

    __shared__ float pl[C];
    __shared__ float yv[HID];
    __shared__ float red[4];
    __shared__ float sc_sh;

    pl[t] = pooled[b * C + t];
    __syncthreads();

    // fc1 + relu: h = t>>4, 16 lanes per h each sum 16 c's, shfl-reduce
    {
        const int h = t >> 4, j = t & 15;
        const float* w1r = w1 + h * C + j * 16;
        const float* plr = pl + j * 16;
        float p = 0.f;
#pragma unroll
        for (int k = 0; k < 16; ++k) p += plr[k] * w1r[k];
        p += __shfl_xor(p, 1, 64);
        p += __shfl_xor(p, 2, 64);
        p += __shfl_xor(p, 4, 64);
        p += __shfl_xor(p, 8, 64);
        if (j == 0) yv[h] = fmaxf(p, 0.f);
    }
    __syncthreads();

    // fc2 for this block's channel c0: d = t; block-reduce 256 terms
    float term = yv[t >> 4] * yv[t & 15] * w2[(size_t)c0 * BD + t];
#pragma unroll
    for (int off = 32; off > 0; off >>= 1) term += __shfl_down(term, off, 64);
    if ((t & 63) == 0) red[t >> 6] = term;
    __syncthreads();
    if (t == 0)
        sc_sh = 1.0f / (1.0f + expf(-((red[0] + red[1]) + (red[2] + red[3]))));
    __syncthreads();
    const float sc = sc_sh;

    vf4* op = reinterpret_cast<vf4*>(out + (size_t)bc * HW);
    v0 *= sc; v1 *= sc; v2 *= sc; v3 *= sc;
    __builtin_nontemporal_store(v0, &op[t]);
    __builtin_nontemporal_store(v1, &op[t + 256]);
    __builtin_nontemporal_store(v2, &op[t + 512]);
    __builtin_nontemporal_store(v3, &op[t + 768]);
}

extern "C" void kernel_launch(void* const* d_in, const int* in_sizes, int n_in,
                              void* d_out, int out_size, void* d_ws, size_t ws_size,
                              hipStream_t stream) {
    const float* x  = (const float*)d_in[0];
    const float* w1 = (const float*)d_in[1];
    const float* w2 = (const float*)d_in[2];
    float* out = (float*)d_out;

    float* pooled = (float*)d_ws;   // B*C floats (32 KB)

    for (int cb = 0; cb < B; cb += CHUNKB) {
        const int bc0 = cb * C;
        pool_kernel<<<CHUNKB * C, 256, 0, stream>>>(x, pooled, bc0);
        scale_kernel<<<CHUNKB * C, 256, 0, stream>>>(x, pooled, w1, w2, out, bc0);
    }
}